// Round 10
// baseline (581.562 us; speedup 1.0000x reference)
//
#include <hip/hip_runtime.h>

typedef unsigned short u16;
typedef __attribute__((ext_vector_type(8))) short short8;
typedef __attribute__((ext_vector_type(4))) float floatx4;

#define SOS 3
#define EOS 4
#define NEGV -10000.0f
#define LOG2E 1.442695041f
#define TWOLOG2E 2.885390082f

__device__ __forceinline__ u16 f2bf(float f) {
  union { float f; unsigned int i; } v; v.f = f;
  unsigned int r = (v.i + 0x7FFFu + ((v.i >> 16) & 1u)) >> 16;
  return (u16)r;
}
__device__ __forceinline__ void gload_lds16(const u16* g, u16* l) {
  __builtin_amdgcn_global_load_lds((const __attribute__((address_space(1))) void*)g,
                                   (__attribute__((address_space(3))) void*)l, 16, 0, 0);
}

// ---------------- gather + wpack fused (independent work, one launch)
// blocks [0,10240): A[m=t*128+b][320] bf16 = embed[x[b][t]][k], zero-pad k>=300
// blocks [10240,10400): Wp[p][320], p = d*512 + j*4 + g (gate-interleaved)
__global__ __launch_bounds__(256) void gw_kernel(const float* __restrict__ embed,
                                                 const int* __restrict__ x,
                                                 const float* __restrict__ Wf,
                                                 const float* __restrict__ Wb,
                                                 u16* __restrict__ A,
                                                 u16* __restrict__ Wp) {
  if (blockIdx.x < 10240) {
    int idx = blockIdx.x * 256 + threadIdx.x;
    int row = idx / 40;
    int c8 = idx - row * 40;
    int col0 = c8 * 8;
    int b = row & 127, t = row >> 7;
    const float* src = embed + (size_t)x[b * 512 + t] * 300 + col0;
    short8 o;
    if (col0 + 8 <= 300) {
      float4 f0 = *(const float4*)(src);
      float4 f1 = *(const float4*)(src + 4);
      o[0] = (short)f2bf(f0.x); o[1] = (short)f2bf(f0.y);
      o[2] = (short)f2bf(f0.z); o[3] = (short)f2bf(f0.w);
      o[4] = (short)f2bf(f1.x); o[5] = (short)f2bf(f1.y);
      o[6] = (short)f2bf(f1.z); o[7] = (short)f2bf(f1.w);
    } else {
      #pragma unroll
      for (int e = 0; e < 8; ++e)
        o[e] = (col0 + e < 300) ? (short)f2bf(src[e]) : (short)0;
    }
    *(short8*)&A[(size_t)row * 320 + col0] = o;
  } else {
    int idx = (blockIdx.x - 10240) * 256 + threadIdx.x;
    int p = idx / 40;
    int c8 = idx - p * 40;
    int col0 = c8 * 8;
    int dd = p >> 9, q = p & 511;
    int j = q >> 2, g = q & 3;
    const float* src = (dd ? Wb : Wf) + (size_t)(g * 128 + j) * 300;
    short8 o;
    #pragma unroll
    for (int e = 0; e < 8; ++e)
      o[e] = (col0 + e < 300) ? (short)f2bf(src[col0 + e]) : (short)0;
    *(short8*)&Wp[(size_t)p * 320 + col0] = o;
  }
}

// ---------------- GEMM: G[65536][1024] bf16 = A @ Wp^T + bias (gate-interleaved cols)
__global__ __launch_bounds__(256) void gemm_kernel(const u16* __restrict__ A,
                                                   const u16* __restrict__ B,
                                                   const float* __restrict__ bf_,
                                                   const float* __restrict__ bb_,
                                                   u16* __restrict__ G) {
  __shared__ u16 At[128 * 32];
  __shared__ u16 Bt[128 * 32];
  const int n = blockIdx.x;
  const int xcd = n & 7, rr = n >> 3;
  const int bx = xcd * 64 + (rr >> 3);
  const int by = rr & 7;
  const int tid = threadIdx.x;
  const int lane = tid & 63;
  const int wave = tid >> 6;
  const int wr = wave >> 1, wc = wave & 1;
  const int arow0 = bx * 128;
  const int bcol0 = by * 128;
  floatx4 acc[4][4] = {};
  const int fq = lane >> 4;
  const int fr = lane & 15;
  const int sr = wave * 32 + (lane >> 2);
  const int sc = (lane & 3) * 8;
  for (int k0 = 0; k0 < 320; k0 += 32) {
    #pragma unroll
    for (int q = 0; q < 2; ++q) {
      gload_lds16(&A[(size_t)(arow0 + sr + q * 16) * 320 + k0 + sc], &At[wave * 1024 + q * 512]);
      gload_lds16(&B[(size_t)(bcol0 + sr + q * 16) * 320 + k0 + sc], &Bt[wave * 1024 + q * 512]);
    }
    __syncthreads();
    short8 af[4], bfr[4];
    #pragma unroll
    for (int mi = 0; mi < 4; ++mi)
      af[mi] = *(const short8*)&At[(wr * 64 + mi * 16 + fr) * 32 + fq * 8];
    #pragma unroll
    for (int ni = 0; ni < 4; ++ni)
      bfr[ni] = *(const short8*)&Bt[(wc * 64 + ni * 16 + fr) * 32 + fq * 8];
    #pragma unroll
    for (int mi = 0; mi < 4; ++mi)
      #pragma unroll
      for (int ni = 0; ni < 4; ++ni)
        acc[mi][ni] = __builtin_amdgcn_mfma_f32_16x16x32_bf16(af[mi], bfr[ni], acc[mi][ni], 0, 0, 0);
    __syncthreads();
  }
  float biasv[4];
  #pragma unroll
  for (int ni = 0; ni < 4; ++ni) {
    int col = bcol0 + wc * 64 + ni * 16 + fr;
    int dd = col >> 9, q = col & 511;
    int jj = q >> 2, gg = q & 3;
    biasv[ni] = (dd ? bb_ : bf_)[gg * 128 + jj];
  }
  #pragma unroll
  for (int mi = 0; mi < 4; ++mi)
    #pragma unroll
    for (int ni = 0; ni < 4; ++ni)
      #pragma unroll
      for (int r = 0; r < 4; ++r) {
        int row = arow0 + wr * 64 + mi * 16 + fq * 4 + r;
        int col = bcol0 + wc * 64 + ni * 16 + fr;
        G[(size_t)row * 1024 + col] = f2bf(acc[mi][ni][r] + biasv[ni]);
      }
}

// ---------------- MFMA LSTM, fused single-phase (unchanged from r9, validated)
__global__ __launch_bounds__(512, 2) void lstm_fused_kernel(const u16* __restrict__ Gp,
                                                            const float* __restrict__ Whh_f,
                                                            const float* __restrict__ Whh_b,
                                                            u16* __restrict__ hs) {
  const int bid = blockIdx.x;
  const int d  = bid >> 5;
  const int b0 = (bid & 31) * 4;
  const int tid = threadIdx.x;
  const int w = tid >> 6, lane = tid & 63;
  const int fr = lane & 15, fq = lane >> 4;
  const float* Wd = d ? Whh_b : Whh_f;

  short8 Wfr[4][4];
  #pragma unroll
  for (int tt = 0; tt < 4; ++tt) {
    const int orow = (fr & 3) * 128 + (16 * w + 4 * tt + (fr >> 2));
    #pragma unroll
    for (int kk = 0; kk < 4; ++kk) {
      const float* src = Wd + (size_t)orow * 128 + fq * 8 + kk * 32;
      float4 x0 = *(const float4*)src;
      float4 x1 = *(const float4*)(src + 4);
      short8 o;
      o[0] = (short)f2bf(x0.x); o[1] = (short)f2bf(x0.y);
      o[2] = (short)f2bf(x0.z); o[3] = (short)f2bf(x0.w);
      o[4] = (short)f2bf(x1.x); o[5] = (short)f2bf(x1.y);
      o[6] = (short)f2bf(x1.z); o[7] = (short)f2bf(x1.w);
      Wfr[tt][kk] = o;
    }
  }

  __shared__ __align__(16) u16 hbuf[2][512];
  for (int i = tid; i < 1024; i += 512) (&hbuf[0][0])[i] = 0;
  __syncthreads();

  const int ts = d ? -1 : 1;
  const int t0 = d ? 511 : 0;
  const int bb  = fr & 3;
  const int ttl = fr >> 2;
  const int jj  = 16 * w + 4 * ttl + fq;

  const int ho0 = bb * 128 + (((fq      + 4 * bb) & 15) << 3);
  const int ho1 = bb * 128 + (((fq + 4  + 4 * bb) & 15) << 3);
  const int ho2 = bb * 128 + (((fq + 8  + 4 * bb) & 15) << 3);
  const int ho3 = bb * 128 + (((fq + 12 + 4 * bb) & 15) << 3);
  const int hwi = bb * 128 + ((((jj >> 3) + 4 * bb) & 15) << 3) + (jj & 7);

  const long long gstep = (long long)ts * 131072;
  const long long hstep = (long long)ts * 256;
  const u16* gld = Gp + (long long)t0 * 131072 + (b0 + bb) * 1024 + d * 512 + 4 * jj;
  u16* hsp = hs + (size_t)(b0 + bb) * 131072 + (long long)t0 * 256 + d * 128 + jj;
  float cst = 0.f;

  uint2 gA, gB, gC;
  gA = *(const uint2*)gld; gld += gstep;
  gB = *(const uint2*)gld; gld += gstep;
  gC = *(const uint2*)gld; gld += gstep;

  u16* hr = &hbuf[0][0];
  u16* hw = &hbuf[1][0];

#define STEPN(GR_, PF_) { \
    short8 f0 = *(const short8*)(hr + ho0); \
    short8 f1 = *(const short8*)(hr + ho1); \
    short8 f2 = *(const short8*)(hr + ho2); \
    short8 f3 = *(const short8*)(hr + ho3); \
    floatx4 a0 = {0.f, 0.f, 0.f, 0.f}; \
    floatx4 a1 = a0, a2 = a0, a3 = a0; \
    a0 = __builtin_amdgcn_mfma_f32_16x16x32_bf16(Wfr[0][0], f0, a0, 0, 0, 0); \
    a1 = __builtin_amdgcn_mfma_f32_16x16x32_bf16(Wfr[1][0], f0, a1, 0, 0, 0); \
    a2 = __builtin_amdgcn_mfma_f32_16x16x32_bf16(Wfr[2][0], f0, a2, 0, 0, 0); \
    a3 = __builtin_amdgcn_mfma_f32_16x16x32_bf16(Wfr[3][0], f0, a3, 0, 0, 0); \
    a0 = __builtin_amdgcn_mfma_f32_16x16x32_bf16(Wfr[0][1], f1, a0, 0, 0, 0); \
    a1 = __builtin_amdgcn_mfma_f32_16x16x32_bf16(Wfr[1][1], f1, a1, 0, 0, 0); \
    a2 = __builtin_amdgcn_mfma_f32_16x16x32_bf16(Wfr[2][1], f1, a2, 0, 0, 0); \
    a3 = __builtin_amdgcn_mfma_f32_16x16x32_bf16(Wfr[3][1], f1, a3, 0, 0, 0); \
    a0 = __builtin_amdgcn_mfma_f32_16x16x32_bf16(Wfr[0][2], f2, a0, 0, 0, 0); \
    a1 = __builtin_amdgcn_mfma_f32_16x16x32_bf16(Wfr[1][2], f2, a1, 0, 0, 0); \
    a2 = __builtin_amdgcn_mfma_f32_16x16x32_bf16(Wfr[2][2], f2, a2, 0, 0, 0); \
    a3 = __builtin_amdgcn_mfma_f32_16x16x32_bf16(Wfr[3][2], f2, a3, 0, 0, 0); \
    a0 = __builtin_amdgcn_mfma_f32_16x16x32_bf16(Wfr[0][3], f3, a0, 0, 0, 0); \
    a1 = __builtin_amdgcn_mfma_f32_16x16x32_bf16(Wfr[1][3], f3, a1, 0, 0, 0); \
    a2 = __builtin_amdgcn_mfma_f32_16x16x32_bf16(Wfr[2][3], f3, a2, 0, 0, 0); \
    a3 = __builtin_amdgcn_mfma_f32_16x16x32_bf16(Wfr[3][3], f3, a3, 0, 0, 0); \
    const bool s0 = (ttl & 1), s1 = (ttl & 2); \
    float p0 = s1 ? (s0 ? a3[0] : a2[0]) : (s0 ? a1[0] : a0[0]); \
    float p1 = s1 ? (s0 ? a3[1] : a2[1]) : (s0 ? a1[1] : a0[1]); \
    float p2 = s1 ? (s0 ? a3[2] : a2[2]) : (s0 ? a1[2] : a0[2]); \
    float p3 = s1 ? (s0 ? a3[3] : a2[3]) : (s0 ? a1[3] : a0[3]); \
    float G0 = __builtin_bit_cast(float, GR_.x << 16); \
    float G1 = __builtin_bit_cast(float, GR_.x & 0xffff0000u); \
    float G2 = __builtin_bit_cast(float, GR_.y << 16); \
    float G3 = __builtin_bit_cast(float, GR_.y & 0xffff0000u); \
    if (PF_) { GR_ = *(const uint2*)gld; gld += gstep; } \
    float i_ = p0 + G0, f_ = p1 + G1, g_ = p2 + G2, o_ = p3 + G3; \
    float p  = __builtin_amdgcn_exp2f(__builtin_amdgcn_fmed3f(g_ * TWOLOG2E, -40.f, 40.f)); \
    float qi = __builtin_amdgcn_exp2f(__builtin_amdgcn_fmed3f(i_ * -LOG2E, -40.f, 40.f)); \
    float qf = __builtin_amdgcn_exp2f(__builtin_amdgcn_fmed3f(f_ * -LOG2E, -40.f, 40.f)); \
    float qo = __builtin_amdgcn_exp2f(__builtin_amdgcn_fmed3f(o_ * -LOG2E, -40.f, 40.f)); \
    float D1 = (1.f + qi) * (p + 1.f); \
    float qf1 = 1.f + qf; \
    float cn = (cst * D1 + (p - 1.f) * qf1) * __builtin_amdgcn_rcpf(qf1 * D1); \
    cst = cn; \
    float v = __builtin_amdgcn_exp2f(__builtin_amdgcn_fmed3f(cn * TWOLOG2E, -40.f, 40.f)); \
    float h = (v - 1.f) * __builtin_amdgcn_rcpf((1.f + qo) * (v + 1.f)); \
    u16 hb = f2bf(h); \
    hw[hwi] = hb; \
    *hsp = hb; \
    hsp += hstep; \
    __builtin_amdgcn_sched_barrier(0); \
    asm volatile("s_waitcnt lgkmcnt(0)"); \
    __builtin_amdgcn_sched_barrier(0); \
    __builtin_amdgcn_s_barrier(); \
    __builtin_amdgcn_sched_barrier(0); \
    u16* tp_ = hr; hr = hw; hw = tp_; \
  }

  #pragma unroll 1
  for (int it = 0; it < 170; ++it) {
    STEPN(gA, true);
    STEPN(gB, true);
    STEPN(gC, true);
  }
  STEPN(gA, false);
  STEPN(gB, false);
#undef STEPN
}

// ---------------- emissions: y[65536][12] = hs(bf16)[65536][256] @ Wout^T + bout
// 4096 blocks x 4 iterations x 4 waves (Ws loaded once per 16 rows)
__global__ __launch_bounds__(256) void emis_kernel(const u16* __restrict__ hs,
                                                   const float* __restrict__ Wout,
                                                   const float* __restrict__ bout,
                                                   float* __restrict__ y) {
  __shared__ float Ws[12 * 256];
  __shared__ float bs[12];
  const int tid = threadIdx.x;
  for (int i = tid; i < 12 * 256; i += 256) Ws[i] = Wout[i];
  if (tid < 12) bs[tid] = bout[tid];
  __syncthreads();
  const int wave = tid >> 6, lane = tid & 63;
  #pragma unroll
  for (int it = 0; it < 4; ++it) {
    const size_t m = ((size_t)blockIdx.x * 4 + it) * 4 + wave;
    uint2 hv = *(const uint2*)&hs[m * 256 + lane * 4];
    float h0 = __builtin_bit_cast(float, hv.x << 16);
    float h1 = __builtin_bit_cast(float, hv.x & 0xffff0000u);
    float h2 = __builtin_bit_cast(float, hv.y << 16);
    float h3 = __builtin_bit_cast(float, hv.y & 0xffff0000u);
    float p[12];
    #pragma unroll
    for (int tg = 0; tg < 12; ++tg) {
      const float* wv = &Ws[tg * 256 + lane * 4];
      p[tg] = h0 * wv[0] + h1 * wv[1] + h2 * wv[2] + h3 * wv[3];
    }
    #pragma unroll
    for (int off = 32; off; off >>= 1)
      #pragma unroll
      for (int tg = 0; tg < 12; ++tg)
        p[tg] += __shfl_xor(p[tg], off);
    if (lane == 0) {
      #pragma unroll
      for (int tg = 0; tg < 12; ++tg)
        y[m * 12 + tg] = p[tg] + bs[tg];
    }
  }
}

// ---------------- CRF: zero-shuffle forward. z broadcast via v_readlane; every
// lane recomputes l0 (lane-0's logsum, same pairwise tree -> bit-identical) from
// the shared E[] + resident etr0 row. No ds_bpermute on the recursion path.
__global__ __launch_bounds__(64) void crf_kernel(const float* __restrict__ y,
                                                 const int* __restrict__ y0,
                                                 const float* __restrict__ trans,
                                                 float* __restrict__ out) {
  const int b = blockIdx.x;
  const int lane = threadIdx.x;
  __shared__ float trs[144];
  for (int i = lane; i < 144; i += 64) trs[i] = trans[i];
  __syncthreads();
  float etr[12], etr0[12];
  float treos = 0.f;
  const int row = (lane < 12) ? lane : 0;
  #pragma unroll
  for (int j = 0; j < 12; ++j) etr[j] = __expf(trs[row * 12 + j]);
  #pragma unroll
  for (int j = 0; j < 12; ++j) etr0[j] = __expf(trs[j]);
  if (lane < 12) treos = trs[EOS * 12 + lane];
  float z = (lane == SOS) ? 0.f : NEGV;
  float base = 0.f;
  const float* yb = y + (size_t)b * 512 * 12;
  const int lr = lane & 15;                 // emission column (garbage for >=12, unused)
  float e0 = yb[(lr < 12) ? lr : 0];
  float e1 = yb[12 + ((lr < 12) ? lr : 0)];
  for (int t = 0; t < 512; ++t) {
    float emit = e0;
    e0 = e1;
    if (t + 2 < 512) e1 = yb[(t + 2) * 12 + ((lr < 12) ? lr : 0)];
    float emit0 = __builtin_bit_cast(float, __builtin_amdgcn_readlane(__builtin_bit_cast(int, emit), 0));
    float E[12];
    #pragma unroll
    for (int j = 0; j < 12; ++j) {
      int zj = __builtin_amdgcn_readlane(__builtin_bit_cast(int, z), j);
      E[j] = __expf(__builtin_bit_cast(float, zj));
    }
    float ex[12], ex0[12];
    #pragma unroll
    for (int j = 0; j < 12; ++j) { ex[j] = E[j] * etr[j]; ex0[j] = E[j] * etr0[j]; }
    float s  = (((ex[0] + ex[1]) + (ex[2] + ex[3])) + ((ex[4] + ex[5]) + (ex[6] + ex[7])))
             + ((ex[8] + ex[9]) + (ex[10] + ex[11]));
    float s0 = (((ex0[0] + ex0[1]) + (ex0[2] + ex0[3])) + ((ex0[4] + ex0[5]) + (ex0[6] + ex0[7])))
             + ((ex0[8] + ex0[9]) + (ex0[10] + ex0[11]));
    float l  = __logf(s)  + emit;
    float l0 = __logf(s0) + emit0;
    z = l - l0;
    base += l0;
  }
  float v = (lane < 12) ? z + treos : -INFINITY;
  float M2 = v;
  #pragma unroll
  for (int off = 32; off; off >>= 1) M2 = fmaxf(M2, __shfl_xor(M2, off));
  float e = __expf(v - M2);
  #pragma unroll
  for (int off = 32; off; off >>= 1) e += __shfl_xor(e, off);
  const float Z = base + M2 + __logf(e);
  const int* y0b = y0 + (size_t)b * 512;
  float acc = 0.f;
  for (int t = lane; t < 512; t += 64) {
    int cur = y0b[t];
    int prev = t ? y0b[t - 1] : SOS;
    acc += yb[t * 12 + cur] + trs[cur * 12 + prev];
  }
  #pragma unroll
  for (int off = 32; off; off >>= 1) acc += __shfl_xor(acc, off);
  if (lane == 0) {
    float gold = acc + trs[EOS * 12 + y0b[511]];
    out[b] = Z - gold;
  }
}

extern "C" void kernel_launch(void* const* d_in, const int* in_sizes, int n_in,
                              void* d_out, int out_size, void* d_ws, size_t ws_size,
                              hipStream_t stream) {
  (void)in_sizes; (void)n_in; (void)out_size; (void)ws_size;
  const int*   x     = (const int*)d_in[0];
  const int*   y0    = (const int*)d_in[1];
  const float* embed = (const float*)d_in[2];
  const float* Wih_f = (const float*)d_in[3];
  const float* Whh_f = (const float*)d_in[4];
  const float* b_f   = (const float*)d_in[5];
  const float* Wih_b = (const float*)d_in[6];
  const float* Whh_b = (const float*)d_in[7];
  const float* b_b   = (const float*)d_in[8];
  const float* Wout  = (const float*)d_in[9];
  const float* bout  = (const float*)d_in[10];
  const float* trans = (const float*)d_in[11];
  float* out = (float*)d_out;

  char* ws = (char*)d_ws;
  u16*   A  = (u16*)(ws);                      // 65536*320 bf16  = 41,943,040 B
  u16*   Wp = (u16*)(ws + 41943040);           // 1024*320  bf16  =    655,360 B
  u16*   G  = (u16*)(ws + 42598400);           // 65536*1024 bf16 = 134,217,728 B
  u16*   hs = (u16*)(ws + 176816128);          // 65536*256 bf16  =  33,554,432 B
  float* yy = (float*)(ws + 210370560);        // 65536*12  f32   =   3,145,728 B

  gw_kernel<<<10400, 256, 0, stream>>>(embed, x, Wih_f, Wih_b, A, Wp);
  gemm_kernel<<<4096, 256, 0, stream>>>(A, Wp, b_f, b_b, G);
  lstm_fused_kernel<<<64, 512, 0, stream>>>(G, Whh_f, Whh_b, hs);
  emis_kernel<<<4096, 256, 0, stream>>>(hs, Wout, bout, yy);
  crf_kernel<<<128, 64, 0, stream>>>(yy, y0, trans, out);
}

// Round 11
// 540.536 us; speedup vs baseline: 1.0759x; 1.0759x over previous
//
#include <hip/hip_runtime.h>

typedef unsigned short u16;
typedef __attribute__((ext_vector_type(8))) short short8;
typedef __attribute__((ext_vector_type(4))) float floatx4;

#define SOS 3
#define EOS 4
#define NEGV -10000.0f
#define LOG2E 1.442695041f
#define TWOLOG2E 2.885390082f

__device__ __forceinline__ u16 f2bf(float f) {
  union { float f; unsigned int i; } v; v.f = f;
  unsigned int r = (v.i + 0x7FFFu + ((v.i >> 16) & 1u)) >> 16;
  return (u16)r;
}
__device__ __forceinline__ void gload_lds16(const u16* g, u16* l) {
  __builtin_amdgcn_global_load_lds((const __attribute__((address_space(1))) void*)g,
                                   (__attribute__((address_space(3))) void*)l, 16, 0, 0);
}

// ---------------- gather: A[m=t*128+b][320] bf16 = embed[x[b][t]][k], zero-pad k>=300
__global__ __launch_bounds__(256) void gather_kernel(const float* __restrict__ embed,
                                                     const int* __restrict__ x,
                                                     u16* __restrict__ A) {
  int idx = blockIdx.x * 256 + threadIdx.x;
  int row = idx / 40;
  int c8 = idx - row * 40;
  int col0 = c8 * 8;
  int b = row & 127, t = row >> 7;
  const float* src = embed + (size_t)x[b * 512 + t] * 300 + col0;
  short8 o;
  if (col0 + 8 <= 300) {
    float4 f0 = *(const float4*)(src);
    float4 f1 = *(const float4*)(src + 4);
    o[0] = (short)f2bf(f0.x); o[1] = (short)f2bf(f0.y);
    o[2] = (short)f2bf(f0.z); o[3] = (short)f2bf(f0.w);
    o[4] = (short)f2bf(f1.x); o[5] = (short)f2bf(f1.y);
    o[6] = (short)f2bf(f1.z); o[7] = (short)f2bf(f1.w);
  } else {
    #pragma unroll
    for (int e = 0; e < 8; ++e)
      o[e] = (col0 + e < 300) ? (short)f2bf(src[e]) : (short)0;
  }
  *(short8*)&A[(size_t)row * 320 + col0] = o;
}

// ---------------- pack W: Wp[p][320], p = d*512 + j*4 + g  (gate-interleaved)
__global__ __launch_bounds__(256) void wpack_kernel(const float* __restrict__ Wf,
                                                    const float* __restrict__ Wb,
                                                    u16* __restrict__ Wp) {
  int idx = blockIdx.x * 256 + threadIdx.x;
  int p = idx / 40;
  int c8 = idx - p * 40;
  int col0 = c8 * 8;
  int dd = p >> 9, q = p & 511;
  int j = q >> 2, g = q & 3;
  const float* src = (dd ? Wb : Wf) + (size_t)(g * 128 + j) * 300;
  short8 o;
  #pragma unroll
  for (int e = 0; e < 8; ++e)
    o[e] = (col0 + e < 300) ? (short)f2bf(src[col0 + e]) : (short)0;
  *(short8*)&Wp[(size_t)p * 320 + col0] = o;
}

// ---------------- GEMM: G[65536][1024] bf16 = A @ Wp^T + bias (gate-interleaved cols)
__global__ __launch_bounds__(256) void gemm_kernel(const u16* __restrict__ A,
                                                   const u16* __restrict__ B,
                                                   const float* __restrict__ bf_,
                                                   const float* __restrict__ bb_,
                                                   u16* __restrict__ G) {
  __shared__ u16 At[128 * 32];
  __shared__ u16 Bt[128 * 32];
  const int n = blockIdx.x;
  const int xcd = n & 7, rr = n >> 3;
  const int bx = xcd * 64 + (rr >> 3);
  const int by = rr & 7;
  const int tid = threadIdx.x;
  const int lane = tid & 63;
  const int wave = tid >> 6;
  const int wr = wave >> 1, wc = wave & 1;
  const int arow0 = bx * 128;
  const int bcol0 = by * 128;
  floatx4 acc[4][4] = {};
  const int fq = lane >> 4;
  const int fr = lane & 15;
  const int sr = wave * 32 + (lane >> 2);
  const int sc = (lane & 3) * 8;
  for (int k0 = 0; k0 < 320; k0 += 32) {
    #pragma unroll
    for (int q = 0; q < 2; ++q) {
      gload_lds16(&A[(size_t)(arow0 + sr + q * 16) * 320 + k0 + sc], &At[wave * 1024 + q * 512]);
      gload_lds16(&B[(size_t)(bcol0 + sr + q * 16) * 320 + k0 + sc], &Bt[wave * 1024 + q * 512]);
    }
    __syncthreads();
    short8 af[4], bfr[4];
    #pragma unroll
    for (int mi = 0; mi < 4; ++mi)
      af[mi] = *(const short8*)&At[(wr * 64 + mi * 16 + fr) * 32 + fq * 8];
    #pragma unroll
    for (int ni = 0; ni < 4; ++ni)
      bfr[ni] = *(const short8*)&Bt[(wc * 64 + ni * 16 + fr) * 32 + fq * 8];
    #pragma unroll
    for (int mi = 0; mi < 4; ++mi)
      #pragma unroll
      for (int ni = 0; ni < 4; ++ni)
        acc[mi][ni] = __builtin_amdgcn_mfma_f32_16x16x32_bf16(af[mi], bfr[ni], acc[mi][ni], 0, 0, 0);
    __syncthreads();
  }
  float biasv[4];
  #pragma unroll
  for (int ni = 0; ni < 4; ++ni) {
    int col = bcol0 + wc * 64 + ni * 16 + fr;
    int dd = col >> 9, q = col & 511;
    int jj = q >> 2, gg = q & 3;
    biasv[ni] = (dd ? bb_ : bf_)[gg * 128 + jj];
  }
  #pragma unroll
  for (int mi = 0; mi < 4; ++mi)
    #pragma unroll
    for (int ni = 0; ni < 4; ++ni)
      #pragma unroll
      for (int r = 0; r < 4; ++r) {
        int row = arow0 + wr * 64 + mi * 16 + fq * 4 + r;
        int col = bcol0 + wc * 64 + ni * 16 + fr;
        G[(size_t)row * 1024 + col] = f2bf(acc[mi][ni][r] + biasv[ni]);
      }
}

// ---------------- MFMA LSTM, fused single-phase (unchanged from r9, validated)
__global__ __launch_bounds__(512, 2) void lstm_fused_kernel(const u16* __restrict__ Gp,
                                                            const float* __restrict__ Whh_f,
                                                            const float* __restrict__ Whh_b,
                                                            u16* __restrict__ hs) {
  const int bid = blockIdx.x;
  const int d  = bid >> 5;
  const int b0 = (bid & 31) * 4;
  const int tid = threadIdx.x;
  const int w = tid >> 6, lane = tid & 63;
  const int fr = lane & 15, fq = lane >> 4;
  const float* Wd = d ? Whh_b : Whh_f;

  short8 Wfr[4][4];
  #pragma unroll
  for (int tt = 0; tt < 4; ++tt) {
    const int orow = (fr & 3) * 128 + (16 * w + 4 * tt + (fr >> 2));
    #pragma unroll
    for (int kk = 0; kk < 4; ++kk) {
      const float* src = Wd + (size_t)orow * 128 + fq * 8 + kk * 32;
      float4 x0 = *(const float4*)src;
      float4 x1 = *(const float4*)(src + 4);
      short8 o;
      o[0] = (short)f2bf(x0.x); o[1] = (short)f2bf(x0.y);
      o[2] = (short)f2bf(x0.z); o[3] = (short)f2bf(x0.w);
      o[4] = (short)f2bf(x1.x); o[5] = (short)f2bf(x1.y);
      o[6] = (short)f2bf(x1.z); o[7] = (short)f2bf(x1.w);
      Wfr[tt][kk] = o;
    }
  }

  __shared__ __align__(16) u16 hbuf[2][512];
  for (int i = tid; i < 1024; i += 512) (&hbuf[0][0])[i] = 0;
  __syncthreads();

  const int ts = d ? -1 : 1;
  const int t0 = d ? 511 : 0;
  const int bb  = fr & 3;
  const int ttl = fr >> 2;
  const int jj  = 16 * w + 4 * ttl + fq;

  const int ho0 = bb * 128 + (((fq      + 4 * bb) & 15) << 3);
  const int ho1 = bb * 128 + (((fq + 4  + 4 * bb) & 15) << 3);
  const int ho2 = bb * 128 + (((fq + 8  + 4 * bb) & 15) << 3);
  const int ho3 = bb * 128 + (((fq + 12 + 4 * bb) & 15) << 3);
  const int hwi = bb * 128 + ((((jj >> 3) + 4 * bb) & 15) << 3) + (jj & 7);

  const long long gstep = (long long)ts * 131072;
  const long long hstep = (long long)ts * 256;
  const u16* gld = Gp + (long long)t0 * 131072 + (b0 + bb) * 1024 + d * 512 + 4 * jj;
  u16* hsp = hs + (size_t)(b0 + bb) * 131072 + (long long)t0 * 256 + d * 128 + jj;
  float cst = 0.f;

  uint2 gA, gB, gC;
  gA = *(const uint2*)gld; gld += gstep;
  gB = *(const uint2*)gld; gld += gstep;
  gC = *(const uint2*)gld; gld += gstep;

  u16* hr = &hbuf[0][0];
  u16* hw = &hbuf[1][0];

#define STEPN(GR_, PF_) { \
    short8 f0 = *(const short8*)(hr + ho0); \
    short8 f1 = *(const short8*)(hr + ho1); \
    short8 f2 = *(const short8*)(hr + ho2); \
    short8 f3 = *(const short8*)(hr + ho3); \
    floatx4 a0 = {0.f, 0.f, 0.f, 0.f}; \
    floatx4 a1 = a0, a2 = a0, a3 = a0; \
    a0 = __builtin_amdgcn_mfma_f32_16x16x32_bf16(Wfr[0][0], f0, a0, 0, 0, 0); \
    a1 = __builtin_amdgcn_mfma_f32_16x16x32_bf16(Wfr[1][0], f0, a1, 0, 0, 0); \
    a2 = __builtin_amdgcn_mfma_f32_16x16x32_bf16(Wfr[2][0], f0, a2, 0, 0, 0); \
    a3 = __builtin_amdgcn_mfma_f32_16x16x32_bf16(Wfr[3][0], f0, a3, 0, 0, 0); \
    a0 = __builtin_amdgcn_mfma_f32_16x16x32_bf16(Wfr[0][1], f1, a0, 0, 0, 0); \
    a1 = __builtin_amdgcn_mfma_f32_16x16x32_bf16(Wfr[1][1], f1, a1, 0, 0, 0); \
    a2 = __builtin_amdgcn_mfma_f32_16x16x32_bf16(Wfr[2][1], f1, a2, 0, 0, 0); \
    a3 = __builtin_amdgcn_mfma_f32_16x16x32_bf16(Wfr[3][1], f1, a3, 0, 0, 0); \
    a0 = __builtin_amdgcn_mfma_f32_16x16x32_bf16(Wfr[0][2], f2, a0, 0, 0, 0); \
    a1 = __builtin_amdgcn_mfma_f32_16x16x32_bf16(Wfr[1][2], f2, a1, 0, 0, 0); \
    a2 = __builtin_amdgcn_mfma_f32_16x16x32_bf16(Wfr[2][2], f2, a2, 0, 0, 0); \
    a3 = __builtin_amdgcn_mfma_f32_16x16x32_bf16(Wfr[3][2], f2, a3, 0, 0, 0); \
    a0 = __builtin_amdgcn_mfma_f32_16x16x32_bf16(Wfr[0][3], f3, a0, 0, 0, 0); \
    a1 = __builtin_amdgcn_mfma_f32_16x16x32_bf16(Wfr[1][3], f3, a1, 0, 0, 0); \
    a2 = __builtin_amdgcn_mfma_f32_16x16x32_bf16(Wfr[2][3], f3, a2, 0, 0, 0); \
    a3 = __builtin_amdgcn_mfma_f32_16x16x32_bf16(Wfr[3][3], f3, a3, 0, 0, 0); \
    const bool s0 = (ttl & 1), s1 = (ttl & 2); \
    float p0 = s1 ? (s0 ? a3[0] : a2[0]) : (s0 ? a1[0] : a0[0]); \
    float p1 = s1 ? (s0 ? a3[1] : a2[1]) : (s0 ? a1[1] : a0[1]); \
    float p2 = s1 ? (s0 ? a3[2] : a2[2]) : (s0 ? a1[2] : a0[2]); \
    float p3 = s1 ? (s0 ? a3[3] : a2[3]) : (s0 ? a1[3] : a0[3]); \
    float G0 = __builtin_bit_cast(float, GR_.x << 16); \
    float G1 = __builtin_bit_cast(float, GR_.x & 0xffff0000u); \
    float G2 = __builtin_bit_cast(float, GR_.y << 16); \
    float G3 = __builtin_bit_cast(float, GR_.y & 0xffff0000u); \
    if (PF_) { GR_ = *(const uint2*)gld; gld += gstep; } \
    float i_ = p0 + G0, f_ = p1 + G1, g_ = p2 + G2, o_ = p3 + G3; \
    float p  = __builtin_amdgcn_exp2f(__builtin_amdgcn_fmed3f(g_ * TWOLOG2E, -40.f, 40.f)); \
    float qi = __builtin_amdgcn_exp2f(__builtin_amdgcn_fmed3f(i_ * -LOG2E, -40.f, 40.f)); \
    float qf = __builtin_amdgcn_exp2f(__builtin_amdgcn_fmed3f(f_ * -LOG2E, -40.f, 40.f)); \
    float qo = __builtin_amdgcn_exp2f(__builtin_amdgcn_fmed3f(o_ * -LOG2E, -40.f, 40.f)); \
    float D1 = (1.f + qi) * (p + 1.f); \
    float qf1 = 1.f + qf; \
    float cn = (cst * D1 + (p - 1.f) * qf1) * __builtin_amdgcn_rcpf(qf1 * D1); \
    cst = cn; \
    float v = __builtin_amdgcn_exp2f(__builtin_amdgcn_fmed3f(cn * TWOLOG2E, -40.f, 40.f)); \
    float h = (v - 1.f) * __builtin_amdgcn_rcpf((1.f + qo) * (v + 1.f)); \
    u16 hb = f2bf(h); \
    hw[hwi] = hb; \
    *hsp = hb; \
    hsp += hstep; \
    __builtin_amdgcn_sched_barrier(0); \
    asm volatile("s_waitcnt lgkmcnt(0)"); \
    __builtin_amdgcn_sched_barrier(0); \
    __builtin_amdgcn_s_barrier(); \
    __builtin_amdgcn_sched_barrier(0); \
    u16* tp_ = hr; hr = hw; hw = tp_; \
  }

  #pragma unroll 1
  for (int it = 0; it < 170; ++it) {
    STEPN(gA, true);
    STEPN(gB, true);
    STEPN(gC, true);
  }
  STEPN(gA, false);
  STEPN(gB, false);
#undef STEPN
}

// ---------------- emissions: y[65536][12] = hs(bf16)[65536][256] @ Wout^T + bout
__global__ __launch_bounds__(256) void emis_kernel(const u16* __restrict__ hs,
                                                   const float* __restrict__ Wout,
                                                   const float* __restrict__ bout,
                                                   float* __restrict__ y) {
  __shared__ float Ws[12 * 256];
  __shared__ float bs[12];
  const int tid = threadIdx.x;
  for (int i = tid; i < 12 * 256; i += 256) Ws[i] = Wout[i];
  if (tid < 12) bs[tid] = bout[tid];
  __syncthreads();
  const int wave = tid >> 6, lane = tid & 63;
  const size_t m = (size_t)blockIdx.x * 4 + wave;
  uint2 hv = *(const uint2*)&hs[m * 256 + lane * 4];
  float h0 = __builtin_bit_cast(float, hv.x << 16);
  float h1 = __builtin_bit_cast(float, hv.x & 0xffff0000u);
  float h2 = __builtin_bit_cast(float, hv.y << 16);
  float h3 = __builtin_bit_cast(float, hv.y & 0xffff0000u);
  float p[12];
  #pragma unroll
  for (int tg = 0; tg < 12; ++tg) {
    const float* wv = &Ws[tg * 256 + lane * 4];
    p[tg] = h0 * wv[0] + h1 * wv[1] + h2 * wv[2] + h3 * wv[3];
  }
  #pragma unroll
  for (int off = 32; off; off >>= 1)
    #pragma unroll
    for (int tg = 0; tg < 12; ++tg)
      p[tg] += __shfl_xor(p[tg], off);
  if (lane == 0) {
    #pragma unroll
    for (int tg = 0; tg < 12; ++tg)
      y[m * 12 + tg] = p[tg] + bs[tg];
  }
}

// ---------------- CRF: exp-domain normalized-u forward. u_j = exp(score_j - base);
// per step: u_raw = (etr-row dot u-broadcast) * e^emit; r = u_raw[0]; u = u_raw*rcp(r);
// base += log(r) (off-chain). Same products as the validated LSE version, minus the
// per-step log->exp round-trip. e^emit precomputed 2 steps ahead.
__global__ __launch_bounds__(64) void crf_kernel(const float* __restrict__ y,
                                                 const int* __restrict__ y0,
                                                 const float* __restrict__ trans,
                                                 float* __restrict__ out) {
  const int b = blockIdx.x;
  const int lane = threadIdx.x;
  __shared__ float trs[144];
  for (int i = lane; i < 144; i += 64) trs[i] = trans[i];
  __syncthreads();
  const int row = (lane < 12) ? lane : 0;
  float etr[12];
  #pragma unroll
  for (int j = 0; j < 12; ++j) etr[j] = __expf(trs[row * 12 + j]);
  float etreos = (lane < 12) ? __expf(trs[EOS * 12 + lane]) : 0.f;
  float u = (lane == SOS) ? 1.f : 0.f;   // exp of initial scores (e^-10000 -> 0)
  float base = 0.f;
  const float* yb = y + (size_t)b * 512 * 12;
  float pe0 = __expf(yb[row]);
  float pe1 = __expf(yb[12 + row]);
  for (int t = 0; t < 512; ++t) {
    float pe = pe0;
    pe0 = pe1;
    if (t + 2 < 512) pe1 = __expf(yb[(t + 2) * 12 + row]);
    float U[12];
    #pragma unroll
    for (int j = 0; j < 12; ++j)
      U[j] = __builtin_bit_cast(float, __builtin_amdgcn_readlane(__builtin_bit_cast(int, u), j));
    float m_[12];
    #pragma unroll
    for (int j = 0; j < 12; ++j) m_[j] = etr[j] * U[j];
    float d = (((m_[0] + m_[1]) + (m_[2] + m_[3])) + ((m_[4] + m_[5]) + (m_[6] + m_[7])))
            + ((m_[8] + m_[9]) + (m_[10] + m_[11]));
    float uraw = d * pe;
    float r = __builtin_bit_cast(float, __builtin_amdgcn_readlane(__builtin_bit_cast(int, uraw), 0));
    base += __logf(r);
    u = uraw * __builtin_amdgcn_rcpf(r);
  }
  float vv = (lane < 12) ? u * etreos : 0.f;
  #pragma unroll
  for (int off = 32; off; off >>= 1) vv += __shfl_xor(vv, off);
  const float Z = base + __logf(vv);
  const int* y0b = y0 + (size_t)b * 512;
  float acc = 0.f;
  for (int t = lane; t < 512; t += 64) {
    int cur = y0b[t];
    int prev = t ? y0b[t - 1] : SOS;
    acc += yb[t * 12 + cur] + trs[cur * 12 + prev];
  }
  #pragma unroll
  for (int off = 32; off; off >>= 1) acc += __shfl_xor(acc, off);
  if (lane == 0) {
    float gold = acc + trs[EOS * 12 + y0b[511]];
    out[b] = Z - gold;
  }
}

extern "C" void kernel_launch(void* const* d_in, const int* in_sizes, int n_in,
                              void* d_out, int out_size, void* d_ws, size_t ws_size,
                              hipStream_t stream) {
  (void)in_sizes; (void)n_in; (void)out_size; (void)ws_size;
  const int*   x     = (const int*)d_in[0];
  const int*   y0    = (const int*)d_in[1];
  const float* embed = (const float*)d_in[2];
  const float* Wih_f = (const float*)d_in[3];
  const float* Whh_f = (const float*)d_in[4];
  const float* b_f   = (const float*)d_in[5];
  const float* Wih_b = (const float*)d_in[6];
  const float* Whh_b = (const float*)d_in[7];
  const float* b_b   = (const float*)d_in[8];
  const float* Wout  = (const float*)d_in[9];
  const float* bout  = (const float*)d_in[10];
  const float* trans = (const float*)d_in[11];
  float* out = (float*)d_out;

  char* ws = (char*)d_ws;
  u16*   A  = (u16*)(ws);                      // 65536*320 bf16  = 41,943,040 B
  u16*   Wp = (u16*)(ws + 41943040);           // 1024*320  bf16  =    655,360 B
  u16*   G  = (u16*)(ws + 42598400);           // 65536*1024 bf16 = 134,217,728 B
  u16*   hs = (u16*)(ws + 176816128);          // 65536*256 bf16  =  33,554,432 B
  float* yy = (float*)(ws + 210370560);        // 65536*12  f32   =   3,145,728 B

  gather_kernel<<<10240, 256, 0, stream>>>(embed, x, A);
  wpack_kernel<<<160, 256, 0, stream>>>(Wih_f, Wih_b, Wp);
  gemm_kernel<<<4096, 256, 0, stream>>>(A, Wp, b_f, b_b, G);
  lstm_fused_kernel<<<64, 512, 0, stream>>>(G, Whh_f, Whh_b, hs);
  emis_kernel<<<16384, 256, 0, stream>>>(hs, Wout, bout, yy);
  crf_kernel<<<128, 64, 0, stream>>>(yy, y0, trans, out);
}